// Round 8
// baseline (237.735 us; speedup 1.0000x reference)
//
#include <hip/hip_runtime.h>
#include <math.h>

// Problem constants (fixed by setup_inputs)
#define HD 32
#define BB 256
#define SS 4096
#define BLK 256           // threads per block (4 waves)
#define NCH 16            // quarter... 16 wave-chunks of 256 positions per row
#define PSTRIDE 36        // floats per wave partial: l, pad[3], y[32] (16B-aligned)

typedef short bf16x8 __attribute__((ext_vector_type(8)));
typedef float f32x4 __attribute__((ext_vector_type(4)));

__device__ __forceinline__ float tanh_fast(float x) {
  float e = __builtin_amdgcn_exp2f(x * 2.8853900817779268f); // 2*log2(e)
  return 1.0f - 2.0f * __builtin_amdgcn_rcpf(e + 1.0f);
}
__device__ __forceinline__ float exp_fast(float x) {
  return __builtin_amdgcn_exp2f(x * 1.4426950408889634f);    // log2(e)
}
__device__ __forceinline__ short bf16_trunc(float x) {      // truncate to bf16
  return (short)(__float_as_uint(x) >> 16);
}
__device__ __forceinline__ float hi_part(float x) {         // fp32, low16=0
  return __uint_as_float(__float_as_uint(x) & 0xffff0000u);
}

// ws layout (bytes): [0, 32K): qvec = qb[b][h] (8192 f32)
//                    [32K, 36K): wkt = B-frag bf16 arrays, 4 x (64 lanes x 8)
//                    [64K, ...): per-wave partials (4096 x PSTRIDE f32)

// p0: block b computes qb[b][:] (threads 0..31); block 0 also emits the
// transposed + hi/lo-split Wk directly in per-lane MFMA B-fragment layout.
__global__ void __launch_bounds__(64) bahdanau_p0(
    const float* __restrict__ fh, const float* __restrict__ Wq,
    const float* __restrict__ bq, const float* __restrict__ Wk,
    const float* __restrict__ bk, float* __restrict__ qvec,
    short* __restrict__ wkt) {
  const int b = blockIdx.x, tid = threadIdx.x;
  if (tid < HD) {
    float acc = bq[tid] + bk[tid];
    const float* fhb = fh + b * HD;
#pragma unroll
    for (int j = 0; j < HD; j++) acc += fhb[j] * Wq[j * HD + tid];
    qvec[b * HD + tid] = acc;
  }
  if (b == 0) {  // tid in [0,64): one MFMA lane each
    const int col = tid & 15, quad = tid >> 4;
#pragma unroll
    for (int j = 0; j < 8; j++) {
      const int k = quad * 8 + j;
      const float w0 = Wk[k * HD + col];
      const float w1 = Wk[k * HD + 16 + col];
      wkt[(0 * 64 + tid) * 8 + j] = bf16_trunc(w0);
      wkt[(1 * 64 + tid) * 8 + j] = bf16_trunc(w0 - hi_part(w0));
      wkt[(2 * 64 + tid) * 8 + j] = bf16_trunc(w1);
      wkt[(3 * 64 + tid) * 8 + j] = bf16_trunc(w1 - hi_part(w1));
    }
  }
}

// Phase 1: ZERO LDS, ZERO barriers. Each wave owns 256 positions of one row
// (4 slices of 64), software-pipelined: prefetch slice s+1 while computing
// slice s. X@Wk on MFMA (bf16 hi/lo split). Per-wave partial (l, y=X^T e).
__global__ void __launch_bounds__(BLK, 3) bahdanau_p1(
    const float* __restrict__ lstm, const float* __restrict__ qvec,
    const short* __restrict__ wkt, const float* __restrict__ Wv,
    const float* __restrict__ bv, float* __restrict__ scores_out,
    float* __restrict__ partials) {
  const int tid = threadIdx.x;
  const int lane = tid & 63;
  const int g = blockIdx.x * 4 + (tid >> 6);   // global wave id [0,4096)
  const int b = g >> 4;
  const int qtr = g & 15;
  const int base = qtr * 256;
  const int col = lane & 15, quad = lane >> 4;

  // B-frags: one 16B load each, same 1KB for every wave -> L1/L2 resident
  const bf16x8 Bh0 = *(const bf16x8*)&wkt[(0 * 64 + lane) * 8];
  const bf16x8 Bl0 = *(const bf16x8*)&wkt[(1 * 64 + lane) * 8];
  const bf16x8 Bh1 = *(const bf16x8*)&wkt[(2 * 64 + lane) * 8];
  const bf16x8 Bl1 = *(const bf16x8*)&wkt[(3 * 64 + lane) * 8];
  const float qb0 = qvec[b * HD + col];
  const float qb1 = qvec[b * HD + 16 + col];
  const float wv0 = Wv[col], wv1 = Wv[16 + col];
  const float bv0 = bv[0];

  const float* gx = lstm + ((size_t)b * SS + base) * HD;
  const float* rp = gx + (size_t)col * HD + quad * 8;  // row col, k-slice quad

  float lAcc = 0.f;
  float yp[8];
#pragma unroll
  for (int j = 0; j < 8; j++) yp[j] = 0.f;

  float4 cur[8];
#pragma unroll
  for (int mt = 0; mt < 4; mt++) {
    cur[2 * mt + 0] = ((const float4*)(rp + (size_t)mt * 16 * HD))[0];
    cur[2 * mt + 1] = ((const float4*)(rp + (size_t)mt * 16 * HD))[1];
  }

#pragma unroll
  for (int s = 0; s < 4; s++) {
    float4 nxt[8];
    if (s < 3) {  // prefetch next slice: stays in flight through the compute
      const float* rn = rp + (size_t)(s + 1) * 64 * HD;
#pragma unroll
      for (int mt = 0; mt < 4; mt++) {
        nxt[2 * mt + 0] = ((const float4*)(rn + (size_t)mt * 16 * HD))[0];
        nxt[2 * mt + 1] = ((const float4*)(rn + (size_t)mt * 16 * HD))[1];
      }
    }

#pragma unroll
    for (int mt = 0; mt < 4; mt++) {
      const float4 XA = cur[2 * mt + 0], XB = cur[2 * mt + 1];
      const float xs[8] = {XA.x, XA.y, XA.z, XA.w, XB.x, XB.y, XB.z, XB.w};
      bf16x8 Ah, Al;
#pragma unroll
      for (int j = 0; j < 8; j++) {
        const float hf = hi_part(xs[j]);
        Ah[j] = bf16_trunc(xs[j]);
        Al[j] = bf16_trunc(xs[j] - hf);
      }
      f32x4 c0 = {0.f, 0.f, 0.f, 0.f}, c1 = {0.f, 0.f, 0.f, 0.f};
      c0 = __builtin_amdgcn_mfma_f32_16x16x32_bf16(Ah, Bh0, c0, 0, 0, 0);
      c1 = __builtin_amdgcn_mfma_f32_16x16x32_bf16(Ah, Bh1, c1, 0, 0, 0);
      c0 = __builtin_amdgcn_mfma_f32_16x16x32_bf16(Al, Bh0, c0, 0, 0, 0);
      c1 = __builtin_amdgcn_mfma_f32_16x16x32_bf16(Al, Bh1, c1, 0, 0, 0);
      c0 = __builtin_amdgcn_mfma_f32_16x16x32_bf16(Ah, Bl0, c0, 0, 0, 0);
      c1 = __builtin_amdgcn_mfma_f32_16x16x32_bf16(Ah, Bl1, c1, 0, 0, 0);

      float esc[4];
#pragma unroll
      for (int r = 0; r < 4; r++) {
        float t = tanh_fast(qb0 + c0[r]) * wv0 + tanh_fast(qb1 + c1[r]) * wv1;
        t += __shfl_xor(t, 1, 64);
        t += __shfl_xor(t, 2, 64);
        t += __shfl_xor(t, 4, 64);
        t += __shfl_xor(t, 8, 64);   // row score in all 16 lanes of the quad
        esc[r] = exp_fast(t + bv0);
      }
      const int srcLane = (col >> 2) * 16;
      const float g0 = __shfl(esc[0], srcLane, 64);
      const float g1 = __shfl(esc[1], srcLane, 64);
      const float g2 = __shfl(esc[2], srcLane, 64);
      const float g3 = __shfl(esc[3], srcLane, 64);
      const int rr = col & 3;
      const float e_m = (rr == 0) ? g0 : (rr == 1) ? g1 : (rr == 2) ? g2 : g3;
      if (lane < 16)
        scores_out[(size_t)b * SS + base + s * 64 + mt * 16 + lane] = e_m;
      lAcc += (lane < 16) ? e_m : 0.f;
#pragma unroll
      for (int j = 0; j < 8; j++) yp[j] = fmaf(e_m, xs[j], yp[j]);
    }

    if (s < 3) {
#pragma unroll
      for (int i = 0; i < 8; i++) cur[i] = nxt[i];
    }
  }

  // reduce y over the 16 rows of this quad's k-slice; l over the wave
#pragma unroll
  for (int j = 0; j < 8; j++) {
    yp[j] += __shfl_xor(yp[j], 1, 64);
    yp[j] += __shfl_xor(yp[j], 2, 64);
    yp[j] += __shfl_xor(yp[j], 4, 64);
    yp[j] += __shfl_xor(yp[j], 8, 64);
  }
#pragma unroll
  for (int off = 32; off >= 1; off >>= 1) lAcc += __shfl_xor(lAcc, off, 64);

  float* p = partials + (size_t)g * PSTRIDE;
  if (lane == 0) p[0] = lAcc;
  if (col == 0) {  // lanes 0,16,32,48: k-slice quad*8..quad*8+7
    float4 y0 = {yp[0], yp[1], yp[2], yp[3]};
    float4 y1 = {yp[4], yp[5], yp[6], yp[7]};
    *(float4*)(p + 4 + quad * 8) = y0;
    *(float4*)(p + 8 + quad * 8) = y1;
  }
}

// Phase 2: 1024 blocks; block scales 1024 consecutive scores (float4/thread)
// of row b = blk>>2. Sub-block 0 also builds ctx = (Y@Wk)/L + bk.
__global__ void __launch_bounds__(BLK) bahdanau_p2(
    const float* __restrict__ partials, const float* __restrict__ Wk,
    const float* __restrict__ bk, float* __restrict__ ctx_out,
    float* __restrict__ scores) {
  const int blk = blockIdx.x;
  const int b = blk >> 2;
  const int tid = threadIdx.x;
  __shared__ float sY[HD];

  float L = 0.f;
#pragma unroll
  for (int c = 0; c < NCH; c++)
    L += partials[(size_t)(b * NCH + c) * PSTRIDE];
  const float invL = __builtin_amdgcn_rcpf(L);

  if ((blk & 3) == 0) {   // block-uniform branch: barrier inside is legal
    if (tid < HD) {
      float y = 0.f;
#pragma unroll
      for (int c = 0; c < NCH; c++)
        y += partials[(size_t)(b * NCH + c) * PSTRIDE + 4 + tid];
      sY[tid] = y;
    }
    __syncthreads();
    if (tid < HD) {
      float c = bk[tid] * L;
#pragma unroll
      for (int j = 0; j < HD; j++) c = fmaf(sY[j], Wk[j * HD + tid], c);
      ctx_out[b * HD + tid] = c * invL;
    }
  }

  float4* srow = (float4*)(scores + (size_t)b * SS + (blk & 3) * 1024);
  float4 s = srow[tid];
  s.x *= invL; s.y *= invL; s.z *= invL; s.w *= invL;
  srow[tid] = s;
}

extern "C" void kernel_launch(void* const* d_in, const int* in_sizes, int n_in,
                              void* d_out, int out_size, void* d_ws,
                              size_t ws_size, hipStream_t stream) {
  const float* lstm = (const float*)d_in[0];
  const float* fh   = (const float*)d_in[1];
  const float* Wq   = (const float*)d_in[2];
  const float* bq   = (const float*)d_in[3];
  const float* Wk   = (const float*)d_in[4];
  const float* bk   = (const float*)d_in[5];
  const float* Wv   = (const float*)d_in[6];
  const float* bv   = (const float*)d_in[7];

  float* out = (float*)d_out;
  float* ctx_out = out;           // context: B*H floats
  float* scores = out + BB * HD;  // att_weights region (e then normalized)

  char* ws = (char*)d_ws;
  float* qvec = (float*)ws;                    // 32 KB
  short* wkt = (short*)(ws + 32768);           // 4 KB
  float* partials = (float*)(ws + 65536);      // 4096 * 36 * 4 B = 576 KB

  bahdanau_p0<<<BB, 64, 0, stream>>>(fh, Wq, bq, Wk, bk, qvec, wkt);
  bahdanau_p1<<<BB * NCH / 4, BLK, 0, stream>>>(lstm, qvec, wkt, Wv, bv,
                                                scores, partials);
  bahdanau_p2<<<BB * 4, BLK, 0, stream>>>(partials, Wk, bk, ctx_out, scores);
}